// Round 1
// baseline (662.388 us; speedup 1.0000x reference)
//
#include <hip/hip_runtime.h>
#include <hip/hip_bf16.h>

#define HH 1024
#define WW 1024
#define CC 8
#define LL 8
#define RAD 25
#define EPSV 1e-6f
#define RB 64   // rows per block in vertical kernels

// ---------------- vertical rolling box sums ----------------

__global__ void vert_oc_kernel(const float* __restrict__ ca, float* __restrict__ A) {
    int x  = blockIdx.x * blockDim.x + threadIdx.x;   // 0..1023
    int c  = blockIdx.z;
    int y0 = blockIdx.y * RB;
    const float* base = ca + (size_t)c * HH * WW + x;
    float acc = 0.f;
    for (int yy = y0 - RAD; yy < y0 + RAD; ++yy)
        if (yy >= 0 && yy < HH) acc += base[(size_t)yy * WW] + EPSV;
    float* Ar = A + (size_t)c * HH * WW + x;
    for (int y = y0; y < y0 + RB; ++y) {
        int yt = y + RAD;
        if (yt < HH) acc += base[(size_t)yt * WW] + EPSV;
        Ar[(size_t)y * WW] = acc;
        int yb = y - RAD;
        if (yb >= 0) acc -= base[(size_t)yb * WW] + EPSV;
    }
}

__global__ void vert_joint_kernel(const float* __restrict__ ca,
                                  const float* __restrict__ nnl,  // nn + l*H*W
                                  float* __restrict__ A) {
    int x  = blockIdx.x * blockDim.x + threadIdx.x;
    int c  = blockIdx.z;
    int y0 = blockIdx.y * RB;
    const float* cb = ca + (size_t)c * HH * WW + x;
    const float* nb = nnl + x;
    float acc = 0.f;
    for (int yy = y0 - RAD; yy < y0 + RAD; ++yy)
        if (yy >= 0 && yy < HH)
            acc += (cb[(size_t)yy * WW] + EPSV) * nb[(size_t)yy * WW];
    float* Ar = A + (size_t)c * HH * WW + x;
    for (int y = y0; y < y0 + RB; ++y) {
        int yt = y + RAD;
        if (yt < HH) acc += (cb[(size_t)yt * WW] + EPSV) * nb[(size_t)yt * WW];
        Ar[(size_t)y * WW] = acc;
        int yb = y - RAD;
        if (yb >= 0) acc -= (cb[(size_t)yb * WW] + EPSV) * nb[(size_t)yb * WW];
    }
}

// ---------------- row prefix scan (1024 elems, 256 threads) ----------------

__device__ __forceinline__ void scan1024(float* row, float* tot, int t) {
    // row[1024] holds values; on exit holds inclusive prefix. Ends with sync.
    float s0 = row[4 * t + 0];
    float s1 = s0 + row[4 * t + 1];
    float s2 = s1 + row[4 * t + 2];
    float s3 = s2 + row[4 * t + 3];
    tot[t] = s3;
    __syncthreads();
    for (int off = 1; off < 256; off <<= 1) {
        float v = (t >= off) ? tot[t - off] : 0.f;
        __syncthreads();
        tot[t] += v;
        __syncthreads();
    }
    float excl = tot[t] - s3;
    row[4 * t + 0] = s0 + excl;
    row[4 * t + 1] = s1 + excl;
    row[4 * t + 2] = s2 + excl;
    row[4 * t + 3] = s3 + excl;
    __syncthreads();
}

__device__ __forceinline__ float window_sum(const float* I, int x) {
    int hiIdx = x + RAD; if (hiIdx > WW - 1) hiIdx = WW - 1;
    float hi = I[hiIdx];
    int loIdx = x - RAD - 1;
    float lo = (loIdx >= 0) ? I[loIdx] : 0.f;
    return hi - lo;
}

// ---------------- horizontal box sum: A -> B ----------------

__global__ void horiz_kernel(const float* __restrict__ A, float* __restrict__ B) {
    int y = blockIdx.x;
    int c = blockIdx.y;
    int t = threadIdx.x;
    __shared__ float row[WW];
    __shared__ float tot[256];
    const float* Ar = A + ((size_t)c * HH + y) * WW;
    row[t]        = Ar[t];
    row[t + 256]  = Ar[t + 256];
    row[t + 512]  = Ar[t + 512];
    row[t + 768]  = Ar[t + 768];
    __syncthreads();
    scan1024(row, tot, t);
    float* Br = B + ((size_t)c * HH + y) * WW;
    #pragma unroll
    for (int k = 0; k < 4; ++k) {
        int x = t + 256 * k;
        Br[x] = window_sum(row, x);
    }
}

// ---------------- combine: out[l,y,x] = sum_c oc * H(A_c)/B_c ----------------

__global__ void combine_kernel(const float* __restrict__ ca,
                               const float* __restrict__ Bn,
                               const float* __restrict__ A,
                               float* __restrict__ outl) {
    int y = blockIdx.x;
    int t = threadIdx.x;
    __shared__ float row[WW];
    __shared__ float tot[256];
    float acc0 = 0.f, acc1 = 0.f, acc2 = 0.f, acc3 = 0.f;
    for (int c = 0; c < CC; ++c) {
        const float* Ar = A + ((size_t)c * HH + y) * WW;
        row[t]       = Ar[t];
        row[t + 256] = Ar[t + 256];
        row[t + 512] = Ar[t + 512];
        row[t + 768] = Ar[t + 768];
        __syncthreads();
        scan1024(row, tot, t);
        const float* cr = ca + ((size_t)c * HH + y) * WW;
        const float* br = Bn + ((size_t)c * HH + y) * WW;
        #pragma unroll
        for (int k = 0; k < 4; ++k) {
            int x = t + 256 * k;
            float h = window_sum(row, x);
            float w = (cr[x] + EPSV) / br[x];
            float v = w * h;
            if      (k == 0) acc0 += v;
            else if (k == 1) acc1 += v;
            else if (k == 2) acc2 += v;
            else             acc3 += v;
        }
        __syncthreads();  // before next c overwrites row
    }
    outl[(size_t)y * WW + t]       = acc0;
    outl[(size_t)y * WW + t + 256] = acc1;
    outl[(size_t)y * WW + t + 512] = acc2;
    outl[(size_t)y * WW + t + 768] = acc3;
}

// ---------------- launch ----------------

extern "C" void kernel_launch(void* const* d_in, const int* in_sizes, int n_in,
                              void* d_out, int out_size, void* d_ws, size_t ws_size,
                              hipStream_t stream) {
    const float* ca = (const float*)d_in[0];            // (8,1024,1024)
    const float* nn = (const float*)d_in[1];            // (1,8,1024,1024)
    float* out = (float*)d_out;                          // (8,1024,1024)

    float* A = (float*)d_ws;                             // 32 MB: vertical sums
    float* B = A + (size_t)CC * HH * WW;                 // 32 MB: BS(oc)

    dim3 blk(256);
    dim3 gv(WW / 256, HH / RB, CC);                      // (4,16,8) = 512 blocks

    vert_oc_kernel<<<gv, blk, 0, stream>>>(ca, A);
    horiz_kernel<<<dim3(HH, CC), blk, 0, stream>>>(A, B);

    for (int l = 0; l < LL; ++l) {
        vert_joint_kernel<<<gv, blk, 0, stream>>>(ca, nn + (size_t)l * HH * WW, A);
        combine_kernel<<<dim3(HH), blk, 0, stream>>>(ca, B, A,
                                                     out + (size_t)l * HH * WW);
    }
}

// Round 3
// 472.393 us; speedup vs baseline: 1.4022x; 1.4022x over previous
//
#include <hip/hip_runtime.h>
#include <hip/hip_bf16.h>

#define HH 1024
#define WW 1024
#define CC 8
#define LL 8
#define RAD 25
#define EPSV 1e-6f
#define RB2 32   // rows per block in vertical kernels

// ---------------- vertical rolling box sums (float2, unrolled) ----------------

__global__ __launch_bounds__(256) void vert_oc2(const float* __restrict__ ca,
                                                float* __restrict__ A) {
    const int rs = WW / 2;                     // row stride in float2
    int t  = threadIdx.x;
    int c  = blockIdx.z;
    int y0 = blockIdx.y * RB2;
    int xi = blockIdx.x * 256 + t;             // float2 column index (0..511)
    const float2* src = (const float2*)ca + (size_t)c * HH * rs + xi;
    float2*       dst = (float2*)A       + (size_t)c * HH * rs + xi;

    float ax = 0.f, ay = 0.f;
    int wlo = y0 - RAD; if (wlo < 0)  wlo = 0;
    int whi = y0 + RAD; if (whi > HH) whi = HH;     // exclusive
    #pragma unroll 5
    for (int yy = wlo; yy < whi; ++yy) {
        float2 v = src[(size_t)yy * rs];
        ax += v.x + EPSV; ay += v.y + EPSV;
    }
    #pragma unroll 4
    for (int y = y0; y < y0 + RB2; ++y) {
        int yt = y + RAD;
        if (yt < HH) {
            float2 v = src[(size_t)yt * rs];
            ax += v.x + EPSV; ay += v.y + EPSV;
        }
        float2 o; o.x = ax; o.y = ay;
        dst[(size_t)y * rs] = o;
        int yb = y - RAD;
        if (yb >= 0) {
            float2 v = src[(size_t)yb * rs];
            ax -= v.x + EPSV; ay -= v.y + EPSV;
        }
    }
}

__global__ __launch_bounds__(256) void vert_joint2(const float* __restrict__ ca,
                                                   const float* __restrict__ nnl,
                                                   float* __restrict__ A) {
    const int rs = WW / 2;
    int t  = threadIdx.x;
    int c  = blockIdx.z;
    int y0 = blockIdx.y * RB2;
    int xi = blockIdx.x * 256 + t;
    const float2* cs = (const float2*)ca  + (size_t)c * HH * rs + xi;
    const float2* ns = (const float2*)nnl + xi;
    float2*       dst = (float2*)A        + (size_t)c * HH * rs + xi;

    float ax = 0.f, ay = 0.f;
    int wlo = y0 - RAD; if (wlo < 0)  wlo = 0;
    int whi = y0 + RAD; if (whi > HH) whi = HH;
    #pragma unroll 5
    for (int yy = wlo; yy < whi; ++yy) {
        float2 v = cs[(size_t)yy * rs];
        float2 w = ns[(size_t)yy * rs];
        ax += (v.x + EPSV) * w.x; ay += (v.y + EPSV) * w.y;
    }
    #pragma unroll 4
    for (int y = y0; y < y0 + RB2; ++y) {
        int yt = y + RAD;
        if (yt < HH) {
            float2 v = cs[(size_t)yt * rs];
            float2 w = ns[(size_t)yt * rs];
            ax += (v.x + EPSV) * w.x; ay += (v.y + EPSV) * w.y;
        }
        float2 o; o.x = ax; o.y = ay;
        dst[(size_t)y * rs] = o;
        int yb = y - RAD;
        if (yb >= 0) {
            float2 v = cs[(size_t)yb * rs];
            float2 w = ns[(size_t)yb * rs];
            ax -= (v.x + EPSV) * w.x; ay -= (v.y + EPSV) * w.y;
        }
    }
}

// ---------------- row prefix scan (1024 elems, 256 threads) ----------------

__device__ __forceinline__ void scan1024(float* row, float* tot, int t) {
    float s0 = row[4 * t + 0];
    float s1 = s0 + row[4 * t + 1];
    float s2 = s1 + row[4 * t + 2];
    float s3 = s2 + row[4 * t + 3];
    tot[t] = s3;
    __syncthreads();
    for (int off = 1; off < 256; off <<= 1) {
        float v = (t >= off) ? tot[t - off] : 0.f;
        __syncthreads();
        tot[t] += v;
        __syncthreads();
    }
    float excl = tot[t] - s3;
    row[4 * t + 0] = s0 + excl;
    row[4 * t + 1] = s1 + excl;
    row[4 * t + 2] = s2 + excl;
    row[4 * t + 3] = s3 + excl;
    __syncthreads();
}

__device__ __forceinline__ float window_sum(const float* I, int x) {
    int hiIdx = x + RAD; if (hiIdx > WW - 1) hiIdx = WW - 1;
    float hi = I[hiIdx];
    int loIdx = x - RAD - 1;
    float lo = (loIdx >= 0) ? I[loIdx] : 0.f;
    return hi - lo;
}

// ---------------- horizontal box sum: A -> B ----------------

__global__ void horiz_kernel(const float* __restrict__ A, float* __restrict__ B) {
    int y = blockIdx.x;
    int c = blockIdx.y;
    int t = threadIdx.x;
    __shared__ float row[WW];
    __shared__ float tot[256];
    const float* Ar = A + ((size_t)c * HH + y) * WW;
    row[t]        = Ar[t];
    row[t + 256]  = Ar[t + 256];
    row[t + 512]  = Ar[t + 512];
    row[t + 768]  = Ar[t + 768];
    __syncthreads();
    scan1024(row, tot, t);
    float* Br = B + ((size_t)c * HH + y) * WW;
    #pragma unroll
    for (int k = 0; k < 4; ++k) {
        int x = t + 256 * k;
        Br[x] = window_sum(row, x);
    }
}

// ---------------- combine: out[l,y,x] = sum_c oc * H(A_c)/B_c ----------------

__global__ void combine_kernel(const float* __restrict__ ca,
                               const float* __restrict__ Bn,
                               const float* __restrict__ A,
                               float* __restrict__ outl) {
    int y = blockIdx.x;
    int t = threadIdx.x;
    __shared__ float row[WW];
    __shared__ float tot[256];
    float acc0 = 0.f, acc1 = 0.f, acc2 = 0.f, acc3 = 0.f;
    for (int c = 0; c < CC; ++c) {
        const float* Ar = A + ((size_t)c * HH + y) * WW;
        row[t]       = Ar[t];
        row[t + 256] = Ar[t + 256];
        row[t + 512] = Ar[t + 512];
        row[t + 768] = Ar[t + 768];
        __syncthreads();
        scan1024(row, tot, t);
        const float* cr = ca + ((size_t)c * HH + y) * WW;
        const float* br = Bn + ((size_t)c * HH + y) * WW;
        #pragma unroll
        for (int k = 0; k < 4; ++k) {
            int x = t + 256 * k;
            float h = window_sum(row, x);
            float w = (cr[x] + EPSV) / br[x];
            float v = w * h;
            if      (k == 0) acc0 += v;
            else if (k == 1) acc1 += v;
            else if (k == 2) acc2 += v;
            else             acc3 += v;
        }
        __syncthreads();
    }
    outl[(size_t)y * WW + t]       = acc0;
    outl[(size_t)y * WW + t + 256] = acc1;
    outl[(size_t)y * WW + t + 512] = acc2;
    outl[(size_t)y * WW + t + 768] = acc3;
}

// ---------------- launch ----------------

extern "C" void kernel_launch(void* const* d_in, const int* in_sizes, int n_in,
                              void* d_out, int out_size, void* d_ws, size_t ws_size,
                              hipStream_t stream) {
    const float* ca = (const float*)d_in[0];            // (8,1024,1024)
    const float* nn = (const float*)d_in[1];            // (1,8,1024,1024)
    float* out = (float*)d_out;                          // (8,1024,1024)

    float* A = (float*)d_ws;                             // 32 MB: vertical sums
    float* B = A + (size_t)CC * HH * WW;                 // 32 MB: BS(oc)

    dim3 blk(256);
    dim3 gv2(2, HH / RB2, CC);                           // (2,32,8) = 512 blocks

    vert_oc2<<<gv2, blk, 0, stream>>>(ca, A);
    horiz_kernel<<<dim3(HH, CC), blk, 0, stream>>>(A, B);

    for (int l = 0; l < LL; ++l) {
        vert_joint2<<<gv2, blk, 0, stream>>>(ca, nn + (size_t)l * HH * WW, A);
        combine_kernel<<<dim3(HH), blk, 0, stream>>>(ca, B, A,
                                                     out + (size_t)l * HH * WW);
    }
}

// Round 4
// 379.695 us; speedup vs baseline: 1.7445x; 1.2441x over previous
//
#include <hip/hip_runtime.h>
#include <hip/hip_bf16.h>

#define HH 1024
#define WW 1024
#define CC 8
#define LL 8
#define RAD 25
#define EPSV 1e-6f
#define SEG 16              // rows per vertical prefix segment
#define NSEG (HH / SEG)     // 64
#define NPL 72              // 64 joint planes + 8 oc planes

typedef unsigned short u16;
typedef unsigned int   u32;

__device__ __forceinline__ u16 bf16r(float x) {
    u32 b = __float_as_uint(x);
    b += 0x7FFFu + ((b >> 16) & 1u);     // round-to-nearest-even
    return (u16)(b >> 16);
}

// =====================================================================
// K1: per-row horizontal 51-window sums for 9 planes (8 joint + 1 oc),
// accumulated as within-segment vertical prefix, stored bf16.
// grid (NSEG, CC) = (64, 8), 512 threads. Each thread owns x = 2t, 2t+1.
// =====================================================================
__global__ __launch_bounds__(512) void hprefix(const float* __restrict__ ca,
                                               const float* __restrict__ nn,
                                               u16* __restrict__ PH,
                                               float* __restrict__ SegT) {
    const int t    = threadIdx.x;          // 0..511
    const int lane = t & 63;
    const int wid  = t >> 6;               // 0..7
    const int yseg = blockIdx.x;           // 0..63
    const int g    = blockIdx.y;           // channel c = g

    __shared__ float ocr[WW];              // oc_g row (+EPS)
    __shared__ float nnr[LL][WW];          // all nn rows
    __shared__ float rowP[WW];             // row prefix
    __shared__ float wtot[8];

    float run[9][2];
    #pragma unroll
    for (int p = 0; p < 9; ++p) { run[p][0] = 0.f; run[p][1] = 0.f; }

    const int x0 = 2 * t, x1 = 2 * t + 1;

    for (int r = 0; r < SEG; ++r) {
        const int y = yseg * SEG + r;
        // ---- stage rows ----
        if (t < 256) {
            float4 v = ((const float4*)(ca + ((size_t)g * HH + y) * WW))[t];
            v.x += EPSV; v.y += EPSV; v.z += EPSV; v.w += EPSV;
            *(float4*)&ocr[t * 4] = v;
        }
        #pragma unroll
        for (int j = 0; j < 4; ++j) {
            int f  = t + 512 * j;          // 0..2047
            int rr = f >> 8, idx = f & 255;
            *(float4*)&nnr[rr][idx * 4] =
                ((const float4*)(nn + ((size_t)rr * HH + y) * WW))[idx];
        }
        __syncthreads();

        #pragma unroll
        for (int p = 0; p < 9; ++p) {
            float p0, p1;
            if (p < 8) {
                p0 = ocr[x0] * nnr[p][x0];
                p1 = ocr[x1] * nnr[p][x1];
            } else {
                p0 = ocr[x0];
                p1 = ocr[x1];
            }
            float s1 = p0 + p1;
            // wave inclusive scan of chunk sums
            float sc = s1;
            #pragma unroll
            for (int off = 1; off < 64; off <<= 1) {
                float v = __shfl_up(sc, off);
                if (lane >= off) sc += v;
            }
            if (lane == 63) wtot[wid] = sc;
            __syncthreads();
            float base = 0.f;
            #pragma unroll
            for (int wi = 0; wi < 8; ++wi)
                if (wi < wid) base += wtot[wi];
            float excl = base + sc - s1;
            rowP[x0] = excl + p0;
            rowP[x1] = excl + s1;
            __syncthreads();
            // horizontal window sums (zero-padded)
            int hi0 = x0 + RAD > WW - 1 ? WW - 1 : x0 + RAD;
            int hi1 = x1 + RAD > WW - 1 ? WW - 1 : x1 + RAD;
            float W0 = rowP[hi0] - (x0 - RAD - 1 >= 0 ? rowP[x0 - RAD - 1] : 0.f);
            float W1 = rowP[hi1] - (x1 - RAD - 1 >= 0 ? rowP[x1 - RAD - 1] : 0.f);
            run[p][0] += W0;
            run[p][1] += W1;

            int pl = (p < 8) ? (g * LL + p) : (64 + g);
            u32 packed = (u32)bf16r(run[p][0]) | ((u32)bf16r(run[p][1]) << 16);
            *(u32*)&PH[((size_t)pl * HH + y) * WW + x0] = packed;
            if (r == SEG - 1) {
                float2 s; s.x = run[p][0]; s.y = run[p][1];
                *(float2*)&SegT[((size_t)pl * NSEG + yseg) * WW + x0] = s;
            }
        }
        __syncthreads();   // staged rows reused until here; next r overwrites
    }
}

// =====================================================================
// K1b: exclusive scan of segment totals over the 64 segments.
// grid (NPL, 4), 256 threads; thread owns one x.
// =====================================================================
__global__ __launch_bounds__(256) void segscan(const float* __restrict__ SegT,
                                               float* __restrict__ Off) {
    int p = blockIdx.x;
    int x = blockIdx.y * 256 + threadIdx.x;
    const float* s = SegT + (size_t)p * NSEG * WW + x;
    float*       o = Off  + (size_t)p * NSEG * WW + x;
    float acc = 0.f;
    for (int sg = 0; sg < NSEG; ++sg) {
        float v = s[(size_t)sg * WW];
        o[(size_t)sg * WW] = acc;
        acc += v;
    }
}

// =====================================================================
// K2: vertical window via prefix difference + combine over c.
// grid (HH), 256 threads; thread owns x = 4t..4t+3. No LDS.
// =====================================================================
struct F4 { float v0, v1, v2, v3; };

__device__ __forceinline__ F4 windowV(const u16* __restrict__ PH,
                                      const float* __restrict__ Off,
                                      int pl, int yhi, int shi, int haslo,
                                      int ylo, int slo, int x0) {
    ushort4 uh = *(const ushort4*)(PH + ((size_t)pl * HH + yhi) * WW + x0);
    float4  oh = *(const float4*)(Off + ((size_t)pl * NSEG + shi) * WW + x0);
    F4 r;
    r.v0 = __uint_as_float((u32)uh.x << 16) + oh.x;
    r.v1 = __uint_as_float((u32)uh.y << 16) + oh.y;
    r.v2 = __uint_as_float((u32)uh.z << 16) + oh.z;
    r.v3 = __uint_as_float((u32)uh.w << 16) + oh.w;
    if (haslo) {
        ushort4 ul = *(const ushort4*)(PH + ((size_t)pl * HH + ylo) * WW + x0);
        float4  ol = *(const float4*)(Off + ((size_t)pl * NSEG + slo) * WW + x0);
        r.v0 -= __uint_as_float((u32)ul.x << 16) + ol.x;
        r.v1 -= __uint_as_float((u32)ul.y << 16) + ol.y;
        r.v2 -= __uint_as_float((u32)ul.z << 16) + ol.z;
        r.v3 -= __uint_as_float((u32)ul.w << 16) + ol.w;
    }
    return r;
}

__global__ __launch_bounds__(256) void vcombine(const float* __restrict__ ca,
                                                const u16* __restrict__ PH,
                                                const float* __restrict__ Off,
                                                float* __restrict__ out) {
    const int y  = blockIdx.x;
    const int t  = threadIdx.x;
    const int x0 = 4 * t;
    const int yhi   = (y + RAD > HH - 1) ? HH - 1 : y + RAD;
    const int shi   = yhi / SEG;
    const int haslo = (y - RAD - 1 >= 0) ? 1 : 0;
    const int ylo   = haslo ? y - RAD - 1 : 0;
    const int slo   = ylo / SEG;

    float a0[LL], a1[LL], a2[LL], a3[LL];
    #pragma unroll
    for (int l = 0; l < LL; ++l) { a0[l] = a1[l] = a2[l] = a3[l] = 0.f; }

    #pragma unroll
    for (int c = 0; c < CC; ++c) {
        F4 Vn = windowV(PH, Off, 64 + c, yhi, shi, haslo, ylo, slo, x0);
        float4 oc4 = *(const float4*)(ca + ((size_t)c * HH + y) * WW + x0);
        float w0 = (oc4.x + EPSV) / Vn.v0;
        float w1 = (oc4.y + EPSV) / Vn.v1;
        float w2 = (oc4.z + EPSV) / Vn.v2;
        float w3 = (oc4.w + EPSV) / Vn.v3;
        #pragma unroll
        for (int l = 0; l < LL; ++l) {
            F4 Vj = windowV(PH, Off, c * LL + l, yhi, shi, haslo, ylo, slo, x0);
            a0[l] += w0 * Vj.v0;
            a1[l] += w1 * Vj.v1;
            a2[l] += w2 * Vj.v2;
            a3[l] += w3 * Vj.v3;
        }
    }
    #pragma unroll
    for (int l = 0; l < LL; ++l) {
        float4 o; o.x = a0[l]; o.y = a1[l]; o.z = a2[l]; o.w = a3[l];
        *(float4*)(out + ((size_t)l * HH + y) * WW + x0) = o;
    }
}

// =====================================================================

extern "C" void kernel_launch(void* const* d_in, const int* in_sizes, int n_in,
                              void* d_out, int out_size, void* d_ws, size_t ws_size,
                              hipStream_t stream) {
    const float* ca = (const float*)d_in[0];   // (8,1024,1024)
    const float* nn = (const float*)d_in[1];   // (1,8,1024,1024)
    float* out = (float*)d_out;                // (8,1024,1024)

    // workspace: PH bf16 [72][H][W] (151 MB) | SegT f32 [72][64][W] (19 MB)
    //            | Off f32 [72][64][W] (19 MB)  => 189 MB total
    u16*   PH   = (u16*)d_ws;
    float* SegT = (float*)((char*)d_ws + (size_t)NPL * HH * WW * sizeof(u16));
    float* Off  = SegT + (size_t)NPL * NSEG * WW;

    hprefix<<<dim3(NSEG, CC), 512, 0, stream>>>(ca, nn, PH, SegT);
    segscan<<<dim3(NPL, 4), 256, 0, stream>>>(SegT, Off);
    vcombine<<<dim3(HH), 256, 0, stream>>>(ca, PH, Off, out);
}

// Round 5
// 286.581 us; speedup vs baseline: 2.3113x; 1.3249x over previous
//
#include <hip/hip_runtime.h>
#include <hip/hip_bf16.h>

#define HH 1024
#define WW 1024
#define CC 8
#define LL 8
#define RAD 25
#define EPSV 1e-6f
#define SEG 16              // rows per vertical prefix segment
#define NSEG (HH / SEG)     // 64
#define NPL 72              // 64 joint planes + 8 oc planes

typedef unsigned short u16;
typedef unsigned int   u32;

__device__ __forceinline__ u16 bf16r(float x) {
    u32 b = __float_as_uint(x);
    b += 0x7FFFu + ((b >> 16) & 1u);     // round-to-nearest-even
    return (u16)(b >> 16);
}

// =====================================================================
// K1: per-row horizontal 51-window sums for 9 planes (8 joint + 1 oc),
// accumulated as within-segment vertical prefix, stored bf16.
// grid (NSEG, CC) = (64, 8), 512 threads. Each thread owns x = 2t, 2t+1.
// =====================================================================
__global__ __launch_bounds__(512) void hprefix(const float* __restrict__ ca,
                                               const float* __restrict__ nn,
                                               u16* __restrict__ PH,
                                               float* __restrict__ SegT) {
    const int t    = threadIdx.x;          // 0..511
    const int lane = t & 63;
    const int wid  = t >> 6;               // 0..7
    const int yseg = blockIdx.x;           // 0..63
    const int g    = blockIdx.y;           // channel c = g

    __shared__ float ocr[WW];              // oc_g row (+EPS)
    __shared__ float nnr[LL][WW];          // all nn rows
    __shared__ float rowP[WW];             // row prefix
    __shared__ float wtot[8];

    float run[9][2];
    #pragma unroll
    for (int p = 0; p < 9; ++p) { run[p][0] = 0.f; run[p][1] = 0.f; }

    const int x0 = 2 * t, x1 = 2 * t + 1;

    for (int r = 0; r < SEG; ++r) {
        const int y = yseg * SEG + r;
        // ---- stage rows ----
        if (t < 256) {
            float4 v = ((const float4*)(ca + ((size_t)g * HH + y) * WW))[t];
            v.x += EPSV; v.y += EPSV; v.z += EPSV; v.w += EPSV;
            *(float4*)&ocr[t * 4] = v;
        }
        #pragma unroll
        for (int j = 0; j < 4; ++j) {
            int f  = t + 512 * j;          // 0..2047
            int rr = f >> 8, idx = f & 255;
            *(float4*)&nnr[rr][idx * 4] =
                ((const float4*)(nn + ((size_t)rr * HH + y) * WW))[idx];
        }
        __syncthreads();

        #pragma unroll
        for (int p = 0; p < 9; ++p) {
            float p0, p1;
            if (p < 8) {
                p0 = ocr[x0] * nnr[p][x0];
                p1 = ocr[x1] * nnr[p][x1];
            } else {
                p0 = ocr[x0];
                p1 = ocr[x1];
            }
            float s1 = p0 + p1;
            // wave inclusive scan of chunk sums
            float sc = s1;
            #pragma unroll
            for (int off = 1; off < 64; off <<= 1) {
                float v = __shfl_up(sc, off);
                if (lane >= off) sc += v;
            }
            if (lane == 63) wtot[wid] = sc;
            __syncthreads();
            float base = 0.f;
            #pragma unroll
            for (int wi = 0; wi < 8; ++wi)
                if (wi < wid) base += wtot[wi];
            float excl = base + sc - s1;
            rowP[x0] = excl + p0;
            rowP[x1] = excl + s1;
            __syncthreads();
            // horizontal window sums (zero-padded)
            int hi0 = x0 + RAD > WW - 1 ? WW - 1 : x0 + RAD;
            int hi1 = x1 + RAD > WW - 1 ? WW - 1 : x1 + RAD;
            float W0 = rowP[hi0] - (x0 - RAD - 1 >= 0 ? rowP[x0 - RAD - 1] : 0.f);
            float W1 = rowP[hi1] - (x1 - RAD - 1 >= 0 ? rowP[x1 - RAD - 1] : 0.f);
            run[p][0] += W0;
            run[p][1] += W1;

            int pl = (p < 8) ? (g * LL + p) : (64 + g);
            u32 packed = (u32)bf16r(run[p][0]) | ((u32)bf16r(run[p][1]) << 16);
            *(u32*)&PH[((size_t)pl * HH + y) * WW + x0] = packed;
            if (r == SEG - 1) {
                float2 s; s.x = run[p][0]; s.y = run[p][1];
                *(float2*)&SegT[((size_t)pl * NSEG + yseg) * WW + x0] = s;
            }
        }
        __syncthreads();   // staged rows reused until here; next r overwrites
    }
}

// =====================================================================
// K1b: exclusive scan of segment totals over the 64 segments.
// grid (NPL, 4), 256 threads; thread owns one x.
// =====================================================================
__global__ __launch_bounds__(256) void segscan(const float* __restrict__ SegT,
                                               float* __restrict__ Off) {
    int p = blockIdx.x;
    int x = blockIdx.y * 256 + threadIdx.x;
    const float* s = SegT + (size_t)p * NSEG * WW + x;
    float*       o = Off  + (size_t)p * NSEG * WW + x;
    float acc = 0.f;
    for (int sg = 0; sg < NSEG; ++sg) {
        float v = s[(size_t)sg * WW];
        o[(size_t)sg * WW] = acc;
        acc += v;
    }
}

// =====================================================================
// K2: vertical window via prefix difference + combine over c.
// grid (HH, LL/2): each block computes 2 labels for one row.
// 256 threads; thread owns x = 4t..4t+3. No LDS, no reduction.
// =====================================================================
struct F4 { float v0, v1, v2, v3; };

__device__ __forceinline__ F4 windowV(const u16* __restrict__ PH,
                                      const float* __restrict__ Off,
                                      int pl, int yhi, int shi, int haslo,
                                      int ylo, int slo, int x0) {
    ushort4 uh = *(const ushort4*)(PH + ((size_t)pl * HH + yhi) * WW + x0);
    float4  oh = *(const float4*)(Off + ((size_t)pl * NSEG + shi) * WW + x0);
    F4 r;
    r.v0 = __uint_as_float((u32)uh.x << 16) + oh.x;
    r.v1 = __uint_as_float((u32)uh.y << 16) + oh.y;
    r.v2 = __uint_as_float((u32)uh.z << 16) + oh.z;
    r.v3 = __uint_as_float((u32)uh.w << 16) + oh.w;
    if (haslo) {
        ushort4 ul = *(const ushort4*)(PH + ((size_t)pl * HH + ylo) * WW + x0);
        float4  ol = *(const float4*)(Off + ((size_t)pl * NSEG + slo) * WW + x0);
        r.v0 -= __uint_as_float((u32)ul.x << 16) + ol.x;
        r.v1 -= __uint_as_float((u32)ul.y << 16) + ol.y;
        r.v2 -= __uint_as_float((u32)ul.z << 16) + ol.z;
        r.v3 -= __uint_as_float((u32)ul.w << 16) + ol.w;
    }
    return r;
}

__global__ __launch_bounds__(256) void vcombine2(const float* __restrict__ ca,
                                                 const u16* __restrict__ PH,
                                                 const float* __restrict__ Off,
                                                 float* __restrict__ out) {
    const int y  = blockIdx.x;
    const int l0 = blockIdx.y * 2;        // this block's 2 labels
    const int t  = threadIdx.x;
    const int x0 = 4 * t;
    const int yhi   = (y + RAD > HH - 1) ? HH - 1 : y + RAD;
    const int shi   = yhi / SEG;
    const int haslo = (y - RAD - 1 >= 0) ? 1 : 0;
    const int ylo   = haslo ? y - RAD - 1 : 0;
    const int slo   = ylo / SEG;

    float a00 = 0.f, a01 = 0.f, a02 = 0.f, a03 = 0.f;
    float a10 = 0.f, a11 = 0.f, a12 = 0.f, a13 = 0.f;

    #pragma unroll
    for (int c = 0; c < CC; ++c) {
        F4 Vn = windowV(PH, Off, 64 + c, yhi, shi, haslo, ylo, slo, x0);
        float4 oc4 = *(const float4*)(ca + ((size_t)c * HH + y) * WW + x0);
        float w0 = (oc4.x + EPSV) / Vn.v0;
        float w1 = (oc4.y + EPSV) / Vn.v1;
        float w2 = (oc4.z + EPSV) / Vn.v2;
        float w3 = (oc4.w + EPSV) / Vn.v3;

        F4 Vj0 = windowV(PH, Off, c * LL + l0,     yhi, shi, haslo, ylo, slo, x0);
        F4 Vj1 = windowV(PH, Off, c * LL + l0 + 1, yhi, shi, haslo, ylo, slo, x0);
        a00 += w0 * Vj0.v0; a01 += w1 * Vj0.v1; a02 += w2 * Vj0.v2; a03 += w3 * Vj0.v3;
        a10 += w0 * Vj1.v0; a11 += w1 * Vj1.v1; a12 += w2 * Vj1.v2; a13 += w3 * Vj1.v3;
    }
    float4 o0; o0.x = a00; o0.y = a01; o0.z = a02; o0.w = a03;
    float4 o1; o1.x = a10; o1.y = a11; o1.z = a12; o1.w = a13;
    *(float4*)(out + ((size_t)(l0 + 0) * HH + y) * WW + x0) = o0;
    *(float4*)(out + ((size_t)(l0 + 1) * HH + y) * WW + x0) = o1;
}

// =====================================================================

extern "C" void kernel_launch(void* const* d_in, const int* in_sizes, int n_in,
                              void* d_out, int out_size, void* d_ws, size_t ws_size,
                              hipStream_t stream) {
    const float* ca = (const float*)d_in[0];   // (8,1024,1024)
    const float* nn = (const float*)d_in[1];   // (1,8,1024,1024)
    float* out = (float*)d_out;                // (8,1024,1024)

    // workspace: PH bf16 [72][H][W] (151 MB) | SegT f32 [72][64][W] (19 MB)
    //            | Off f32 [72][64][W] (19 MB)  => 189 MB total
    u16*   PH   = (u16*)d_ws;
    float* SegT = (float*)((char*)d_ws + (size_t)NPL * HH * WW * sizeof(u16));
    float* Off  = SegT + (size_t)NPL * NSEG * WW;

    hprefix<<<dim3(NSEG, CC), 512, 0, stream>>>(ca, nn, PH, SegT);
    segscan<<<dim3(NPL, 4), 256, 0, stream>>>(SegT, Off);
    vcombine2<<<dim3(HH, LL / 2), 256, 0, stream>>>(ca, PH, Off, out);
}

// Round 6
// 286.512 us; speedup vs baseline: 2.3119x; 1.0002x over previous
//
#include <hip/hip_runtime.h>
#include <hip/hip_bf16.h>

#define HH 1024
#define WW 1024
#define CC 8
#define LL 8
#define RAD 25
#define EPSV 1e-6f
#define SEG 16              // rows per vertical prefix segment
#define NSEG (HH / SEG)     // 64
#define NPL 72              // 64 joint planes + 8 oc planes

typedef unsigned short u16;
typedef unsigned int   u32;

__device__ __forceinline__ u16 bf16r(float x) {
    u32 b = __float_as_uint(x);
    b += 0x7FFFu + ((b >> 16) & 1u);     // round-to-nearest-even
    return (u16)(b >> 16);
}

// =====================================================================
// K1: per-row horizontal 51-window sums for 9 planes (8 joint + 1 oc),
// accumulated as within-segment vertical prefix, stored bf16.
// grid (NSEG, CC) = (64, 8), 512 threads, thread owns x = 2t, 2t+1.
// No input staging (direct coalesced float2 loads, L2/L3-hot);
// all 9 plane scans batched between barriers -> 2 syncs/row.
// =====================================================================
__global__ __launch_bounds__(512) void hprefix2(const float* __restrict__ ca,
                                                const float* __restrict__ nn,
                                                u16* __restrict__ PH,
                                                float* __restrict__ SegT) {
    const int t    = threadIdx.x;          // 0..511
    const int lane = t & 63;
    const int wid  = t >> 6;               // 0..7
    const int yseg = blockIdx.x;           // 0..63
    const int g    = blockIdx.y;           // channel c = g

    __shared__ float rowP[9][WW];          // 36 KB: per-plane row prefix
    __shared__ float wtot[9][8];

    float run[9][2];
    #pragma unroll
    for (int p = 0; p < 9; ++p) { run[p][0] = 0.f; run[p][1] = 0.f; }

    const int x0 = 2 * t, x1 = 2 * t + 1;
    const int hi0 = (x0 + RAD > WW - 1) ? WW - 1 : x0 + RAD;
    const int hi1 = (x1 + RAD > WW - 1) ? WW - 1 : x1 + RAD;
    const int lo0 = x0 - RAD - 1;          // may be negative
    const int lo1 = x1 - RAD - 1;

    for (int r = 0; r < SEG; ++r) {
        const int y = yseg * SEG + r;

        float2 cv = ((const float2*)(ca + ((size_t)g * HH + y) * WW))[t];
        cv.x += EPSV; cv.y += EPSV;

        float pv1[9], sc9[9];
        // ---- 9 independent wave scans (no barriers) ----
        #pragma unroll
        for (int p = 0; p < 9; ++p) {
            float p0, p1;
            if (p < 8) {
                float2 nv = ((const float2*)(nn + ((size_t)p * HH + y) * WW))[t];
                p0 = cv.x * nv.x; p1 = cv.y * nv.y;
            } else {
                p0 = cv.x; p1 = cv.y;
            }
            float sc = p0 + p1;
            #pragma unroll
            for (int off = 1; off < 64; off <<= 1) {
                float v = __shfl_up(sc, off);
                if (lane >= off) sc += v;
            }
            if (lane == 63) wtot[p][wid] = sc;
            pv1[p] = p1;
            sc9[p] = sc;
        }
        __syncthreads();                   // wtot ready

        // ---- add cross-wave bases, publish prefixes ----
        #pragma unroll
        for (int p = 0; p < 9; ++p) {
            float base = 0.f;
            #pragma unroll
            for (int wi = 0; wi < 7; ++wi)
                if (wi < wid) base += wtot[p][wi];
            float inc = base + sc9[p];     // inclusive prefix at x1
            rowP[p][x1] = inc;
            rowP[p][x0] = inc - pv1[p];
        }
        __syncthreads();                   // rowP ready

        // ---- window sums, vertical running prefix, store ----
        #pragma unroll
        for (int p = 0; p < 9; ++p) {
            float W0 = rowP[p][hi0] - (lo0 >= 0 ? rowP[p][lo0] : 0.f);
            float W1 = rowP[p][hi1] - (lo1 >= 0 ? rowP[p][lo1] : 0.f);
            run[p][0] += W0;
            run[p][1] += W1;

            int pl = (p < 8) ? (g * LL + p) : (64 + g);
            u32 packed = (u32)bf16r(run[p][0]) | ((u32)bf16r(run[p][1]) << 16);
            *(u32*)&PH[((size_t)pl * HH + y) * WW + x0] = packed;
            if (r == SEG - 1) {
                float2 s; s.x = run[p][0]; s.y = run[p][1];
                *(float2*)&SegT[((size_t)pl * NSEG + yseg) * WW + x0] = s;
            }
        }
        // next iteration's rowP writes are after its own first barrier; safe
    }
}

// =====================================================================
// K1b: exclusive scan of segment totals over the 64 segments.
// grid (NPL, 4), 256 threads; thread owns one x.
// =====================================================================
__global__ __launch_bounds__(256) void segscan(const float* __restrict__ SegT,
                                               float* __restrict__ Off) {
    int p = blockIdx.x;
    int x = blockIdx.y * 256 + threadIdx.x;
    const float* s = SegT + (size_t)p * NSEG * WW + x;
    float*       o = Off  + (size_t)p * NSEG * WW + x;
    float acc = 0.f;
    for (int sg = 0; sg < NSEG; ++sg) {
        float v = s[(size_t)sg * WW];
        o[(size_t)sg * WW] = acc;
        acc += v;
    }
}

// =====================================================================
// K2: vertical window via prefix difference + combine over c.
// grid (HH, LL/2): each block computes 2 labels for one row.
// 256 threads; thread owns x = 4t..4t+3. No LDS, no reduction.
// =====================================================================
struct F4 { float v0, v1, v2, v3; };

__device__ __forceinline__ F4 windowV(const u16* __restrict__ PH,
                                      const float* __restrict__ Off,
                                      int pl, int yhi, int shi, int haslo,
                                      int ylo, int slo, int x0) {
    ushort4 uh = *(const ushort4*)(PH + ((size_t)pl * HH + yhi) * WW + x0);
    float4  oh = *(const float4*)(Off + ((size_t)pl * NSEG + shi) * WW + x0);
    F4 r;
    r.v0 = __uint_as_float((u32)uh.x << 16) + oh.x;
    r.v1 = __uint_as_float((u32)uh.y << 16) + oh.y;
    r.v2 = __uint_as_float((u32)uh.z << 16) + oh.z;
    r.v3 = __uint_as_float((u32)uh.w << 16) + oh.w;
    if (haslo) {
        ushort4 ul = *(const ushort4*)(PH + ((size_t)pl * HH + ylo) * WW + x0);
        float4  ol = *(const float4*)(Off + ((size_t)pl * NSEG + slo) * WW + x0);
        r.v0 -= __uint_as_float((u32)ul.x << 16) + ol.x;
        r.v1 -= __uint_as_float((u32)ul.y << 16) + ol.y;
        r.v2 -= __uint_as_float((u32)ul.z << 16) + ol.z;
        r.v3 -= __uint_as_float((u32)ul.w << 16) + ol.w;
    }
    return r;
}

__global__ __launch_bounds__(256) void vcombine2(const float* __restrict__ ca,
                                                 const u16* __restrict__ PH,
                                                 const float* __restrict__ Off,
                                                 float* __restrict__ out) {
    const int y  = blockIdx.x;
    const int l0 = blockIdx.y * 2;        // this block's 2 labels
    const int t  = threadIdx.x;
    const int x0 = 4 * t;
    const int yhi   = (y + RAD > HH - 1) ? HH - 1 : y + RAD;
    const int shi   = yhi / SEG;
    const int haslo = (y - RAD - 1 >= 0) ? 1 : 0;
    const int ylo   = haslo ? y - RAD - 1 : 0;
    const int slo   = ylo / SEG;

    float a00 = 0.f, a01 = 0.f, a02 = 0.f, a03 = 0.f;
    float a10 = 0.f, a11 = 0.f, a12 = 0.f, a13 = 0.f;

    #pragma unroll
    for (int c = 0; c < CC; ++c) {
        F4 Vn = windowV(PH, Off, 64 + c, yhi, shi, haslo, ylo, slo, x0);
        float4 oc4 = *(const float4*)(ca + ((size_t)c * HH + y) * WW + x0);
        float w0 = (oc4.x + EPSV) / Vn.v0;
        float w1 = (oc4.y + EPSV) / Vn.v1;
        float w2 = (oc4.z + EPSV) / Vn.v2;
        float w3 = (oc4.w + EPSV) / Vn.v3;

        F4 Vj0 = windowV(PH, Off, c * LL + l0,     yhi, shi, haslo, ylo, slo, x0);
        F4 Vj1 = windowV(PH, Off, c * LL + l0 + 1, yhi, shi, haslo, ylo, slo, x0);
        a00 += w0 * Vj0.v0; a01 += w1 * Vj0.v1; a02 += w2 * Vj0.v2; a03 += w3 * Vj0.v3;
        a10 += w0 * Vj1.v0; a11 += w1 * Vj1.v1; a12 += w2 * Vj1.v2; a13 += w3 * Vj1.v3;
    }
    float4 o0; o0.x = a00; o0.y = a01; o0.z = a02; o0.w = a03;
    float4 o1; o1.x = a10; o1.y = a11; o1.z = a12; o1.w = a13;
    *(float4*)(out + ((size_t)(l0 + 0) * HH + y) * WW + x0) = o0;
    *(float4*)(out + ((size_t)(l0 + 1) * HH + y) * WW + x0) = o1;
}

// =====================================================================

extern "C" void kernel_launch(void* const* d_in, const int* in_sizes, int n_in,
                              void* d_out, int out_size, void* d_ws, size_t ws_size,
                              hipStream_t stream) {
    const float* ca = (const float*)d_in[0];   // (8,1024,1024)
    const float* nn = (const float*)d_in[1];   // (1,8,1024,1024)
    float* out = (float*)d_out;                // (8,1024,1024)

    // workspace: PH bf16 [72][H][W] (151 MB) | SegT f32 [72][64][W] (19 MB)
    //            | Off f32 [72][64][W] (19 MB)  => 189 MB total
    u16*   PH   = (u16*)d_ws;
    float* SegT = (float*)((char*)d_ws + (size_t)NPL * HH * WW * sizeof(u16));
    float* Off  = SegT + (size_t)NPL * NSEG * WW;

    hprefix2<<<dim3(NSEG, CC), 512, 0, stream>>>(ca, nn, PH, SegT);
    segscan<<<dim3(NPL, 4), 256, 0, stream>>>(SegT, Off);
    vcombine2<<<dim3(HH, LL / 2), 256, 0, stream>>>(ca, PH, Off, out);
}

// Round 7
// 256.169 us; speedup vs baseline: 2.5857x; 1.1184x over previous
//
#include <hip/hip_runtime.h>
#include <hip/hip_bf16.h>

#define HH 1024
#define WW 1024
#define CC 8
#define LL 8
#define RAD 25
#define EPSV 1e-6f
#define SEG 16              // rows per vertical prefix segment
#define NSEG (HH / SEG)     // 64
#define NPL 72              // 64 joint planes + 8 oc planes

typedef unsigned short u16;
typedef unsigned int   u32;

__device__ __forceinline__ u16 bf16r(float x) {
    u32 b = __float_as_uint(x);
    b += 0x7FFFu + ((b >> 16) & 1u);     // round-to-nearest-even
    return (u16)(b >> 16);
}

// =====================================================================
// K1: per-row horizontal 51-window sums, one WAVE per (segment, c, plane)
// task. Lane owns 16 contiguous x in registers: local prefix (VALU),
// one 6-step shfl scan of lane totals, prefix -> padded LDS, 2 reads/elem
// for the window difference. Zero __syncthreads, no cross-wave traffic.
// grid: 4608 wave-tasks = 1152 blocks x 4 waves.
// =====================================================================
__global__ __launch_bounds__(256) void hprefix3(const float* __restrict__ ca,
                                                const float* __restrict__ nn,
                                                u16* __restrict__ PH,
                                                float* __restrict__ SegT) {
    const int t    = threadIdx.x;
    const int lane = t & 63;
    const int w    = t >> 6;               // wave in block 0..3
    const int task = blockIdx.x * 4 + w;   // 0..4607
    const int yseg = task / (CC * 9);
    const int rem  = task - yseg * (CC * 9);
    const int c    = rem / 9;
    const int p    = rem - c * 9;          // 0..7 joint, 8 = oc plane

    __shared__ float Pbuf[4][1088];        // pad-17 layout: word = e + (e>>4)
    float* __restrict__ lp = Pbuf[w];

    const int pl = (p < 8) ? (c * 8 + p) : (64 + c);
    const float* carow = ca + (size_t)c * HH * WW + 16 * lane;
    const float* nnrow = nn + (size_t)(p < 8 ? p : 0) * HH * WW + 16 * lane;
    const int x0 = 16 * lane;

    float run[16];
    #pragma unroll
    for (int i = 0; i < 16; ++i) run[i] = 0.f;

    for (int r = 0; r < SEG; ++r) {
        const int y = yseg * SEG + r;
        float a[16];
        #pragma unroll
        for (int k = 0; k < 4; ++k) {
            float4 v = *(const float4*)(carow + (size_t)y * WW + 4 * k);
            a[4*k+0] = v.x + EPSV; a[4*k+1] = v.y + EPSV;
            a[4*k+2] = v.z + EPSV; a[4*k+3] = v.w + EPSV;
        }
        if (p < 8) {
            #pragma unroll
            for (int k = 0; k < 4; ++k) {
                float4 v = *(const float4*)(nnrow + (size_t)y * WW + 4 * k);
                a[4*k+0] *= v.x; a[4*k+1] *= v.y;
                a[4*k+2] *= v.z; a[4*k+3] *= v.w;
            }
        }
        // register-local inclusive prefix over the 16-chunk
        #pragma unroll
        for (int i = 1; i < 16; ++i) a[i] += a[i-1];
        // wave exclusive scan of chunk totals (6 shfl)
        float tot = a[15];
        float sc  = tot;
        #pragma unroll
        for (int off = 1; off < 64; off <<= 1) {
            float v = __shfl_up(sc, off);
            if (lane >= off) sc += v;
        }
        float base = sc - tot;             // exclusive prefix of chunks
        // absolute row prefix -> LDS (padded, conflict-free)
        {
            const int b = 17 * lane;
            #pragma unroll
            for (int i = 0; i < 16; ++i) lp[b + i] = a[i] + base;
        }
        // window sums via prefix difference; vertical running prefix
        #pragma unroll
        for (int i = 0; i < 16; ++i) {
            int eh = x0 + i + RAD; eh = (eh > WW - 1) ? WW - 1 : eh;
            int el = x0 + i - RAD - 1;
            float hi = lp[eh + (eh >> 4)];
            float lo = (el >= 0) ? lp[el + (el >> 4)] : 0.f;
            run[i] += hi - lo;
        }
        // store bf16 running prefix (2x 16B stores)
        u32 pk[8];
        #pragma unroll
        for (int j = 0; j < 8; ++j)
            pk[j] = (u32)bf16r(run[2*j]) | ((u32)bf16r(run[2*j+1]) << 16);
        u16* dst = PH + ((size_t)pl * HH + y) * WW + x0;
        *(uint4*)(dst)     = make_uint4(pk[0], pk[1], pk[2], pk[3]);
        *(uint4*)(dst + 8) = make_uint4(pk[4], pk[5], pk[6], pk[7]);
    }
    // segment totals (f32, exact)
    float* st = SegT + ((size_t)pl * NSEG + yseg) * WW + x0;
    #pragma unroll
    for (int k = 0; k < 4; ++k) {
        float4 v; v.x = run[4*k+0]; v.y = run[4*k+1];
        v.z = run[4*k+2]; v.w = run[4*k+3];
        *(float4*)(st + 4 * k) = v;
    }
}

// =====================================================================
// K1b: exclusive scan of segment totals over the 64 segments.
// grid (NPL, 4), 256 threads; thread owns one x.
// =====================================================================
__global__ __launch_bounds__(256) void segscan(const float* __restrict__ SegT,
                                               float* __restrict__ Off) {
    int p = blockIdx.x;
    int x = blockIdx.y * 256 + threadIdx.x;
    const float* s = SegT + (size_t)p * NSEG * WW + x;
    float*       o = Off  + (size_t)p * NSEG * WW + x;
    float acc = 0.f;
    for (int sg = 0; sg < NSEG; ++sg) {
        float v = s[(size_t)sg * WW];
        o[(size_t)sg * WW] = acc;
        acc += v;
    }
}

// =====================================================================
// K2: vertical window via prefix difference + combine over c.
// grid (HH, LL/2): each block computes 2 labels for one row.
// 256 threads; thread owns x = 4t..4t+3. No LDS, no reduction.
// =====================================================================
struct F4 { float v0, v1, v2, v3; };

__device__ __forceinline__ F4 windowV(const u16* __restrict__ PH,
                                      const float* __restrict__ Off,
                                      int pl, int yhi, int shi, int haslo,
                                      int ylo, int slo, int x0) {
    ushort4 uh = *(const ushort4*)(PH + ((size_t)pl * HH + yhi) * WW + x0);
    float4  oh = *(const float4*)(Off + ((size_t)pl * NSEG + shi) * WW + x0);
    F4 r;
    r.v0 = __uint_as_float((u32)uh.x << 16) + oh.x;
    r.v1 = __uint_as_float((u32)uh.y << 16) + oh.y;
    r.v2 = __uint_as_float((u32)uh.z << 16) + oh.z;
    r.v3 = __uint_as_float((u32)uh.w << 16) + oh.w;
    if (haslo) {
        ushort4 ul = *(const ushort4*)(PH + ((size_t)pl * HH + ylo) * WW + x0);
        float4  ol = *(const float4*)(Off + ((size_t)pl * NSEG + slo) * WW + x0);
        r.v0 -= __uint_as_float((u32)ul.x << 16) + ol.x;
        r.v1 -= __uint_as_float((u32)ul.y << 16) + ol.y;
        r.v2 -= __uint_as_float((u32)ul.z << 16) + ol.z;
        r.v3 -= __uint_as_float((u32)ul.w << 16) + ol.w;
    }
    return r;
}

__global__ __launch_bounds__(256) void vcombine2(const float* __restrict__ ca,
                                                 const u16* __restrict__ PH,
                                                 const float* __restrict__ Off,
                                                 float* __restrict__ out) {
    const int y  = blockIdx.x;
    const int l0 = blockIdx.y * 2;        // this block's 2 labels
    const int t  = threadIdx.x;
    const int x0 = 4 * t;
    const int yhi   = (y + RAD > HH - 1) ? HH - 1 : y + RAD;
    const int shi   = yhi / SEG;
    const int haslo = (y - RAD - 1 >= 0) ? 1 : 0;
    const int ylo   = haslo ? y - RAD - 1 : 0;
    const int slo   = ylo / SEG;

    float a00 = 0.f, a01 = 0.f, a02 = 0.f, a03 = 0.f;
    float a10 = 0.f, a11 = 0.f, a12 = 0.f, a13 = 0.f;

    #pragma unroll
    for (int c = 0; c < CC; ++c) {
        F4 Vn = windowV(PH, Off, 64 + c, yhi, shi, haslo, ylo, slo, x0);
        float4 oc4 = *(const float4*)(ca + ((size_t)c * HH + y) * WW + x0);
        float w0 = (oc4.x + EPSV) / Vn.v0;
        float w1 = (oc4.y + EPSV) / Vn.v1;
        float w2 = (oc4.z + EPSV) / Vn.v2;
        float w3 = (oc4.w + EPSV) / Vn.v3;

        F4 Vj0 = windowV(PH, Off, c * LL + l0,     yhi, shi, haslo, ylo, slo, x0);
        F4 Vj1 = windowV(PH, Off, c * LL + l0 + 1, yhi, shi, haslo, ylo, slo, x0);
        a00 += w0 * Vj0.v0; a01 += w1 * Vj0.v1; a02 += w2 * Vj0.v2; a03 += w3 * Vj0.v3;
        a10 += w0 * Vj1.v0; a11 += w1 * Vj1.v1; a12 += w2 * Vj1.v2; a13 += w3 * Vj1.v3;
    }
    float4 o0; o0.x = a00; o0.y = a01; o0.z = a02; o0.w = a03;
    float4 o1; o1.x = a10; o1.y = a11; o1.z = a12; o1.w = a13;
    *(float4*)(out + ((size_t)(l0 + 0) * HH + y) * WW + x0) = o0;
    *(float4*)(out + ((size_t)(l0 + 1) * HH + y) * WW + x0) = o1;
}

// =====================================================================

extern "C" void kernel_launch(void* const* d_in, const int* in_sizes, int n_in,
                              void* d_out, int out_size, void* d_ws, size_t ws_size,
                              hipStream_t stream) {
    const float* ca = (const float*)d_in[0];   // (8,1024,1024)
    const float* nn = (const float*)d_in[1];   // (1,8,1024,1024)
    float* out = (float*)d_out;                // (8,1024,1024)

    // workspace: PH bf16 [72][H][W] (151 MB) | SegT f32 [72][64][W] (19 MB)
    //            | Off f32 [72][64][W] (19 MB)  => 189 MB total
    u16*   PH   = (u16*)d_ws;
    float* SegT = (float*)((char*)d_ws + (size_t)NPL * HH * WW * sizeof(u16));
    float* Off  = SegT + (size_t)NPL * NSEG * WW;

    hprefix3<<<dim3(4608 / 4), 256, 0, stream>>>(ca, nn, PH, SegT);
    segscan<<<dim3(NPL, 4), 256, 0, stream>>>(SegT, Off);
    vcombine2<<<dim3(HH, LL / 2), 256, 0, stream>>>(ca, PH, Off, out);
}

// Round 8
// 216.599 us; speedup vs baseline: 3.0581x; 1.1827x over previous
//
#include <hip/hip_runtime.h>
#include <hip/hip_bf16.h>

#define HH 1024
#define WW 1024
#define CC 8
#define LL 8
#define RAD 25
#define EPSV 1e-6f
#define SEG 16              // rows per vertical prefix segment
#define NSEG (HH / SEG)     // 64
#define NPL 72              // 64 joint planes + 8 oc planes

typedef unsigned short u16;
typedef unsigned int   u32;

__device__ __forceinline__ u16 bf16r(float x) {
    u32 b = __float_as_uint(x);
    b += 0x7FFFu + ((b >> 16) & 1u);     // round-to-nearest-even
    return (u16)(b >> 16);
}

// =====================================================================
// K1: per-row horizontal 51-window sums, one WAVE per (segment, c, plane)
// task. Lane owns 16 contiguous x in registers: local prefix (VALU),
// one 6-step shfl scan of lane totals, prefix -> padded LDS, 2 reads/elem
// for the window difference. Zero __syncthreads, no cross-wave traffic.
// grid: 4608 wave-tasks = 1152 blocks x 4 waves.
// =====================================================================
__global__ __launch_bounds__(256) void hprefix3(const float* __restrict__ ca,
                                                const float* __restrict__ nn,
                                                u16* __restrict__ PH,
                                                float* __restrict__ SegT) {
    const int t    = threadIdx.x;
    const int lane = t & 63;
    const int w    = t >> 6;               // wave in block 0..3
    const int task = blockIdx.x * 4 + w;   // 0..4607
    const int yseg = task / (CC * 9);
    const int rem  = task - yseg * (CC * 9);
    const int c    = rem / 9;
    const int p    = rem - c * 9;          // 0..7 joint, 8 = oc plane

    __shared__ float Pbuf[4][1088];        // pad-17 layout: word = e + (e>>4)
    float* __restrict__ lp = Pbuf[w];

    const int pl = (p < 8) ? (c * 8 + p) : (64 + c);
    const float* carow = ca + (size_t)c * HH * WW + 16 * lane;
    const float* nnrow = nn + (size_t)(p < 8 ? p : 0) * HH * WW + 16 * lane;
    const int x0 = 16 * lane;

    float run[16];
    #pragma unroll
    for (int i = 0; i < 16; ++i) run[i] = 0.f;

    for (int r = 0; r < SEG; ++r) {
        const int y = yseg * SEG + r;
        float a[16];
        #pragma unroll
        for (int k = 0; k < 4; ++k) {
            float4 v = *(const float4*)(carow + (size_t)y * WW + 4 * k);
            a[4*k+0] = v.x + EPSV; a[4*k+1] = v.y + EPSV;
            a[4*k+2] = v.z + EPSV; a[4*k+3] = v.w + EPSV;
        }
        if (p < 8) {
            #pragma unroll
            for (int k = 0; k < 4; ++k) {
                float4 v = *(const float4*)(nnrow + (size_t)y * WW + 4 * k);
                a[4*k+0] *= v.x; a[4*k+1] *= v.y;
                a[4*k+2] *= v.z; a[4*k+3] *= v.w;
            }
        }
        // register-local inclusive prefix over the 16-chunk
        #pragma unroll
        for (int i = 1; i < 16; ++i) a[i] += a[i-1];
        // wave exclusive scan of chunk totals (6 shfl)
        float tot = a[15];
        float sc  = tot;
        #pragma unroll
        for (int off = 1; off < 64; off <<= 1) {
            float v = __shfl_up(sc, off);
            if (lane >= off) sc += v;
        }
        float base = sc - tot;             // exclusive prefix of chunks
        // absolute row prefix -> LDS (padded, conflict-free)
        {
            const int b = 17 * lane;
            #pragma unroll
            for (int i = 0; i < 16; ++i) lp[b + i] = a[i] + base;
        }
        // window sums via prefix difference; vertical running prefix
        #pragma unroll
        for (int i = 0; i < 16; ++i) {
            int eh = x0 + i + RAD; eh = (eh > WW - 1) ? WW - 1 : eh;
            int el = x0 + i - RAD - 1;
            float hi = lp[eh + (eh >> 4)];
            float lo = (el >= 0) ? lp[el + (el >> 4)] : 0.f;
            run[i] += hi - lo;
        }
        // store bf16 running prefix (2x 16B stores)
        u32 pk[8];
        #pragma unroll
        for (int j = 0; j < 8; ++j)
            pk[j] = (u32)bf16r(run[2*j]) | ((u32)bf16r(run[2*j+1]) << 16);
        u16* dst = PH + ((size_t)pl * HH + y) * WW + x0;
        *(uint4*)(dst)     = make_uint4(pk[0], pk[1], pk[2], pk[3]);
        *(uint4*)(dst + 8) = make_uint4(pk[4], pk[5], pk[6], pk[7]);
    }
    // segment totals (f32, exact)
    float* st = SegT + ((size_t)pl * NSEG + yseg) * WW + x0;
    #pragma unroll
    for (int k = 0; k < 4; ++k) {
        float4 v; v.x = run[4*k+0]; v.y = run[4*k+1];
        v.z = run[4*k+2]; v.w = run[4*k+3];
        *(float4*)(st + 4 * k) = v;
    }
}

// =====================================================================
// K1b: exclusive scan of segment totals over the 64 segments.
// grid (NPL, 4), 256 threads; thread owns one x.
// =====================================================================
__global__ __launch_bounds__(256) void segscan(const float* __restrict__ SegT,
                                               float* __restrict__ Off) {
    int p = blockIdx.x;
    int x = blockIdx.y * 256 + threadIdx.x;
    const float* s = SegT + (size_t)p * NSEG * WW + x;
    float*       o = Off  + (size_t)p * NSEG * WW + x;
    float acc = 0.f;
    for (int sg = 0; sg < NSEG; ++sg) {
        float v = s[(size_t)sg * WW];
        o[(size_t)sg * WW] = acc;
        acc += v;
    }
}

// =====================================================================
// windowV: vertical 51-window of a plane via prefix difference.
// =====================================================================
struct F4 { float v0, v1, v2, v3; };

__device__ __forceinline__ F4 windowV(const u16* __restrict__ PH,
                                      const float* __restrict__ Off,
                                      int pl, int yhi, int shi, int haslo,
                                      int ylo, int slo, int x0) {
    ushort4 uh = *(const ushort4*)(PH + ((size_t)pl * HH + yhi) * WW + x0);
    float4  oh = *(const float4*)(Off + ((size_t)pl * NSEG + shi) * WW + x0);
    F4 r;
    r.v0 = __uint_as_float((u32)uh.x << 16) + oh.x;
    r.v1 = __uint_as_float((u32)uh.y << 16) + oh.y;
    r.v2 = __uint_as_float((u32)uh.z << 16) + oh.z;
    r.v3 = __uint_as_float((u32)uh.w << 16) + oh.w;
    if (haslo) {
        ushort4 ul = *(const ushort4*)(PH + ((size_t)pl * HH + ylo) * WW + x0);
        float4  ol = *(const float4*)(Off + ((size_t)pl * NSEG + slo) * WW + x0);
        r.v0 -= __uint_as_float((u32)ul.x << 16) + ol.x;
        r.v1 -= __uint_as_float((u32)ul.y << 16) + ol.y;
        r.v2 -= __uint_as_float((u32)ul.z << 16) + ol.z;
        r.v3 -= __uint_as_float((u32)ul.w << 16) + ol.w;
    }
    return r;
}

// =====================================================================
// K1c: weights Wgt[c][y][x] = (ca+EPS) / Vn. grid 1024 blocks,
// XCD-swizzled so consecutive y land on the same XCD (L2 window reuse).
// =====================================================================
__global__ __launch_bounds__(256) void wgtk(const float* __restrict__ ca,
                                            const u16* __restrict__ PH,
                                            const float* __restrict__ Off,
                                            float* __restrict__ Wgt) {
    const int b   = blockIdx.x;            // 0..1023
    const int y   = (b & 7) * 128 + (b >> 3);   // bijective XCD swizzle
    const int t   = threadIdx.x;
    const int x0  = 4 * t;
    const int yhi   = (y + RAD > HH - 1) ? HH - 1 : y + RAD;
    const int shi   = yhi / SEG;
    const int haslo = (y - RAD - 1 >= 0) ? 1 : 0;
    const int ylo   = haslo ? y - RAD - 1 : 0;
    const int slo   = ylo / SEG;

    #pragma unroll
    for (int c = 0; c < CC; ++c) {
        F4 Vn = windowV(PH, Off, 64 + c, yhi, shi, haslo, ylo, slo, x0);
        float4 oc4 = *(const float4*)(ca + ((size_t)c * HH + y) * WW + x0);
        float4 w;
        w.x = (oc4.x + EPSV) / Vn.v0;
        w.y = (oc4.y + EPSV) / Vn.v1;
        w.z = (oc4.z + EPSV) / Vn.v2;
        w.w = (oc4.w + EPSV) / Vn.v3;
        *(float4*)(Wgt + ((size_t)c * HH + y) * WW + x0) = w;
    }
}

// =====================================================================
// K2: out[l,y,x] = sum_c Wgt * V(joint). grid 4096 blocks, XCD-swizzled
// (512 consecutive works per XCD = 128 consecutive y x 4 l-pairs).
// =====================================================================
__global__ __launch_bounds__(256) void vcombine3(const float* __restrict__ Wgt,
                                                 const u16* __restrict__ PH,
                                                 const float* __restrict__ Off,
                                                 float* __restrict__ out) {
    const int b    = blockIdx.x;           // 0..4095
    const int work = (b & 7) * 512 + (b >> 3);  // bijective XCD swizzle
    const int y    = work >> 2;
    const int l0   = (work & 3) << 1;
    const int t  = threadIdx.x;
    const int x0 = 4 * t;
    const int yhi   = (y + RAD > HH - 1) ? HH - 1 : y + RAD;
    const int shi   = yhi / SEG;
    const int haslo = (y - RAD - 1 >= 0) ? 1 : 0;
    const int ylo   = haslo ? y - RAD - 1 : 0;
    const int slo   = ylo / SEG;

    float a00 = 0.f, a01 = 0.f, a02 = 0.f, a03 = 0.f;
    float a10 = 0.f, a11 = 0.f, a12 = 0.f, a13 = 0.f;

    #pragma unroll
    for (int c = 0; c < CC; ++c) {
        float4 w4 = *(const float4*)(Wgt + ((size_t)c * HH + y) * WW + x0);
        F4 Vj0 = windowV(PH, Off, c * LL + l0,     yhi, shi, haslo, ylo, slo, x0);
        F4 Vj1 = windowV(PH, Off, c * LL + l0 + 1, yhi, shi, haslo, ylo, slo, x0);
        a00 += w4.x * Vj0.v0; a01 += w4.y * Vj0.v1;
        a02 += w4.z * Vj0.v2; a03 += w4.w * Vj0.v3;
        a10 += w4.x * Vj1.v0; a11 += w4.y * Vj1.v1;
        a12 += w4.z * Vj1.v2; a13 += w4.w * Vj1.v3;
    }
    float4 o0; o0.x = a00; o0.y = a01; o0.z = a02; o0.w = a03;
    float4 o1; o1.x = a10; o1.y = a11; o1.z = a12; o1.w = a13;
    *(float4*)(out + ((size_t)(l0 + 0) * HH + y) * WW + x0) = o0;
    *(float4*)(out + ((size_t)(l0 + 1) * HH + y) * WW + x0) = o1;
}

// =====================================================================

extern "C" void kernel_launch(void* const* d_in, const int* in_sizes, int n_in,
                              void* d_out, int out_size, void* d_ws, size_t ws_size,
                              hipStream_t stream) {
    const float* ca = (const float*)d_in[0];   // (8,1024,1024)
    const float* nn = (const float*)d_in[1];   // (1,8,1024,1024)
    float* out = (float*)d_out;                // (8,1024,1024)

    // workspace: PH bf16 [72][H][W] (151 MB) | SegT f32 (19 MB)
    //            | Off f32 (19 MB) | Wgt f32 [8][H][W] (33.5 MB) => 222 MB
    u16*   PH   = (u16*)d_ws;
    float* SegT = (float*)((char*)d_ws + (size_t)NPL * HH * WW * sizeof(u16));
    float* Off  = SegT + (size_t)NPL * NSEG * WW;
    float* Wgt  = Off  + (size_t)NPL * NSEG * WW;

    hprefix3<<<dim3(4608 / 4), 256, 0, stream>>>(ca, nn, PH, SegT);
    segscan<<<dim3(NPL, 4), 256, 0, stream>>>(SegT, Off);
    wgtk<<<dim3(HH), 256, 0, stream>>>(ca, PH, Off, Wgt);
    vcombine3<<<dim3(HH * 4), 256, 0, stream>>>(Wgt, PH, Off, out);
}

// Round 10
// 200.985 us; speedup vs baseline: 3.2957x; 1.0777x over previous
//
#include <hip/hip_runtime.h>
#include <hip/hip_bf16.h>

#define HH 1024
#define WW 1024
#define CC 8
#define LL 8
#define RAD 25
#define EPSV 1e-6f
#define SEG 16              // rows per vertical prefix segment
#define NSEG (HH / SEG)     // 64
#define NPL 72              // 64 joint planes + 8 oc planes

typedef unsigned short u16;
typedef unsigned int   u32;
typedef u32   u32x4 __attribute__((ext_vector_type(4)));
typedef float f32x4 __attribute__((ext_vector_type(4)));

__device__ __forceinline__ u16 bf16r(float x) {
    u32 b = __float_as_uint(x);
    b += 0x7FFFu + ((b >> 16) & 1u);     // round-to-nearest-even
    return (u16)(b >> 16);
}

// =====================================================================
// K1: per-row horizontal 51-window sums, one WAVE per (segment, c, plane)
// task. XCD-contiguous task swizzle: each XCD owns 144 consecutive blocks
// = 8 complete ysegs, so ca-row sharers (9 planes) and nn-row sharers
// (8 c's) hit the same L2. PH/SegT stores are non-temporal to keep the
// input set resident in L2/L3.
// grid: 4608 wave-tasks = 1152 blocks x 4 waves.
// =====================================================================
__global__ __launch_bounds__(256) void hprefix4(const float* __restrict__ ca,
                                                const float* __restrict__ nn,
                                                u16* __restrict__ PH,
                                                float* __restrict__ SegT) {
    const int t    = threadIdx.x;
    const int lane = t & 63;
    const int w    = t >> 6;               // wave in block 0..3
    const int blk  = blockIdx.x;           // 0..1151
    // XCD-contiguous remap: blocks dispatch round-robin over 8 XCDs;
    // give XCD (blk&7) the contiguous task chunk [ (blk&7)*576, +576 ).
    const int task = ((blk & 7) * 144 + (blk >> 3)) * 4 + w;   // 0..4607
    const int yseg = task / (CC * 9);
    const int rem  = task - yseg * (CC * 9);
    const int c    = rem / 9;
    const int p    = rem - c * 9;          // 0..7 joint, 8 = oc plane

    __shared__ float Pbuf[4][1088];        // pad-17 layout: word = e + (e>>4)
    float* __restrict__ lp = Pbuf[w];

    const int pl = (p < 8) ? (c * 8 + p) : (64 + c);
    const float* carow = ca + (size_t)c * HH * WW + 16 * lane;
    const float* nnrow = nn + (size_t)(p < 8 ? p : 0) * HH * WW + 16 * lane;
    const int x0 = 16 * lane;

    float run[16];
    #pragma unroll
    for (int i = 0; i < 16; ++i) run[i] = 0.f;

    for (int r = 0; r < SEG; ++r) {
        const int y = yseg * SEG + r;
        float a[16];
        #pragma unroll
        for (int k = 0; k < 4; ++k) {
            float4 v = *(const float4*)(carow + (size_t)y * WW + 4 * k);
            a[4*k+0] = v.x + EPSV; a[4*k+1] = v.y + EPSV;
            a[4*k+2] = v.z + EPSV; a[4*k+3] = v.w + EPSV;
        }
        if (p < 8) {
            #pragma unroll
            for (int k = 0; k < 4; ++k) {
                float4 v = *(const float4*)(nnrow + (size_t)y * WW + 4 * k);
                a[4*k+0] *= v.x; a[4*k+1] *= v.y;
                a[4*k+2] *= v.z; a[4*k+3] *= v.w;
            }
        }
        // register-local inclusive prefix over the 16-chunk
        #pragma unroll
        for (int i = 1; i < 16; ++i) a[i] += a[i-1];
        // wave exclusive scan of chunk totals (6 shfl)
        float tot = a[15];
        float sc  = tot;
        #pragma unroll
        for (int off = 1; off < 64; off <<= 1) {
            float v = __shfl_up(sc, off);
            if (lane >= off) sc += v;
        }
        float base = sc - tot;             // exclusive prefix of chunks
        // absolute row prefix -> LDS (padded, conflict-free)
        {
            const int b = 17 * lane;
            #pragma unroll
            for (int i = 0; i < 16; ++i) lp[b + i] = a[i] + base;
        }
        // window sums via prefix difference; vertical running prefix
        #pragma unroll
        for (int i = 0; i < 16; ++i) {
            int eh = x0 + i + RAD; eh = (eh > WW - 1) ? WW - 1 : eh;
            int el = x0 + i - RAD - 1;
            float hi = lp[eh + (eh >> 4)];
            float lo = (el >= 0) ? lp[el + (el >> 4)] : 0.f;
            run[i] += hi - lo;
        }
        // store bf16 running prefix (2x 16B non-temporal stores)
        u32 pk[8];
        #pragma unroll
        for (int j = 0; j < 8; ++j)
            pk[j] = (u32)bf16r(run[2*j]) | ((u32)bf16r(run[2*j+1]) << 16);
        u16* dst = PH + ((size_t)pl * HH + y) * WW + x0;
        u32x4 q0; q0.x = pk[0]; q0.y = pk[1]; q0.z = pk[2]; q0.w = pk[3];
        u32x4 q1; q1.x = pk[4]; q1.y = pk[5]; q1.z = pk[6]; q1.w = pk[7];
        __builtin_nontemporal_store(q0, (u32x4*)dst);
        __builtin_nontemporal_store(q1, (u32x4*)(dst + 8));
    }
    // segment totals (f32, exact), non-temporal
    float* st = SegT + ((size_t)pl * NSEG + yseg) * WW + x0;
    #pragma unroll
    for (int k = 0; k < 4; ++k) {
        f32x4 v; v.x = run[4*k+0]; v.y = run[4*k+1];
        v.z = run[4*k+2]; v.w = run[4*k+3];
        __builtin_nontemporal_store(v, (f32x4*)(st + 4 * k));
    }
}

// =====================================================================
// K1b: exclusive scan of segment totals over the 64 segments.
// grid (NPL, 4), 256 threads; thread owns one x.
// =====================================================================
__global__ __launch_bounds__(256) void segscan(const float* __restrict__ SegT,
                                               float* __restrict__ Off) {
    int p = blockIdx.x;
    int x = blockIdx.y * 256 + threadIdx.x;
    const float* s = SegT + (size_t)p * NSEG * WW + x;
    float*       o = Off  + (size_t)p * NSEG * WW + x;
    float acc = 0.f;
    for (int sg = 0; sg < NSEG; ++sg) {
        float v = s[(size_t)sg * WW];
        o[(size_t)sg * WW] = acc;
        acc += v;
    }
}

// =====================================================================
// windowV: vertical 51-window of a plane via prefix difference.
// =====================================================================
struct F4 { float v0, v1, v2, v3; };

__device__ __forceinline__ F4 windowV(const u16* __restrict__ PH,
                                      const float* __restrict__ Off,
                                      int pl, int yhi, int shi, int haslo,
                                      int ylo, int slo, int x0) {
    ushort4 uh = *(const ushort4*)(PH + ((size_t)pl * HH + yhi) * WW + x0);
    float4  oh = *(const float4*)(Off + ((size_t)pl * NSEG + shi) * WW + x0);
    F4 r;
    r.v0 = __uint_as_float((u32)uh.x << 16) + oh.x;
    r.v1 = __uint_as_float((u32)uh.y << 16) + oh.y;
    r.v2 = __uint_as_float((u32)uh.z << 16) + oh.z;
    r.v3 = __uint_as_float((u32)uh.w << 16) + oh.w;
    if (haslo) {
        ushort4 ul = *(const ushort4*)(PH + ((size_t)pl * HH + ylo) * WW + x0);
        float4  ol = *(const float4*)(Off + ((size_t)pl * NSEG + slo) * WW + x0);
        r.v0 -= __uint_as_float((u32)ul.x << 16) + ol.x;
        r.v1 -= __uint_as_float((u32)ul.y << 16) + ol.y;
        r.v2 -= __uint_as_float((u32)ul.z << 16) + ol.z;
        r.v3 -= __uint_as_float((u32)ul.w << 16) + ol.w;
    }
    return r;
}

// =====================================================================
// K1c: weights Wgt[c][y][x] = (ca+EPS) / Vn. grid 1024 blocks,
// XCD-swizzled so consecutive y land on the same XCD (L2 window reuse).
// =====================================================================
__global__ __launch_bounds__(256) void wgtk(const float* __restrict__ ca,
                                            const u16* __restrict__ PH,
                                            const float* __restrict__ Off,
                                            float* __restrict__ Wgt) {
    const int b   = blockIdx.x;            // 0..1023
    const int y   = (b & 7) * 128 + (b >> 3);   // bijective XCD swizzle
    const int t   = threadIdx.x;
    const int x0  = 4 * t;
    const int yhi   = (y + RAD > HH - 1) ? HH - 1 : y + RAD;
    const int shi   = yhi / SEG;
    const int haslo = (y - RAD - 1 >= 0) ? 1 : 0;
    const int ylo   = haslo ? y - RAD - 1 : 0;
    const int slo   = ylo / SEG;

    #pragma unroll
    for (int c = 0; c < CC; ++c) {
        F4 Vn = windowV(PH, Off, 64 + c, yhi, shi, haslo, ylo, slo, x0);
        float4 oc4 = *(const float4*)(ca + ((size_t)c * HH + y) * WW + x0);
        float4 w;
        w.x = (oc4.x + EPSV) / Vn.v0;
        w.y = (oc4.y + EPSV) / Vn.v1;
        w.z = (oc4.z + EPSV) / Vn.v2;
        w.w = (oc4.w + EPSV) / Vn.v3;
        *(float4*)(Wgt + ((size_t)c * HH + y) * WW + x0) = w;
    }
}

// =====================================================================
// K2: out[l,y,x] = sum_c Wgt * V(joint). grid 4096 blocks, XCD-swizzled
// (512 consecutive works per XCD = 128 consecutive y x 4 l-pairs).
// =====================================================================
__global__ __launch_bounds__(256) void vcombine3(const float* __restrict__ Wgt,
                                                 const u16* __restrict__ PH,
                                                 const float* __restrict__ Off,
                                                 float* __restrict__ out) {
    const int b    = blockIdx.x;           // 0..4095
    const int work = (b & 7) * 512 + (b >> 3);  // bijective XCD swizzle
    const int y    = work >> 2;
    const int l0   = (work & 3) << 1;
    const int t  = threadIdx.x;
    const int x0 = 4 * t;
    const int yhi   = (y + RAD > HH - 1) ? HH - 1 : y + RAD;
    const int shi   = yhi / SEG;
    const int haslo = (y - RAD - 1 >= 0) ? 1 : 0;
    const int ylo   = haslo ? y - RAD - 1 : 0;
    const int slo   = ylo / SEG;

    float a00 = 0.f, a01 = 0.f, a02 = 0.f, a03 = 0.f;
    float a10 = 0.f, a11 = 0.f, a12 = 0.f, a13 = 0.f;

    #pragma unroll
    for (int c = 0; c < CC; ++c) {
        float4 w4 = *(const float4*)(Wgt + ((size_t)c * HH + y) * WW + x0);
        F4 Vj0 = windowV(PH, Off, c * LL + l0,     yhi, shi, haslo, ylo, slo, x0);
        F4 Vj1 = windowV(PH, Off, c * LL + l0 + 1, yhi, shi, haslo, ylo, slo, x0);
        a00 += w4.x * Vj0.v0; a01 += w4.y * Vj0.v1;
        a02 += w4.z * Vj0.v2; a03 += w4.w * Vj0.v3;
        a10 += w4.x * Vj1.v0; a11 += w4.y * Vj1.v1;
        a12 += w4.z * Vj1.v2; a13 += w4.w * Vj1.v3;
    }
    float4 o0; o0.x = a00; o0.y = a01; o0.z = a02; o0.w = a03;
    float4 o1; o1.x = a10; o1.y = a11; o1.z = a12; o1.w = a13;
    *(float4*)(out + ((size_t)(l0 + 0) * HH + y) * WW + x0) = o0;
    *(float4*)(out + ((size_t)(l0 + 1) * HH + y) * WW + x0) = o1;
}

// =====================================================================

extern "C" void kernel_launch(void* const* d_in, const int* in_sizes, int n_in,
                              void* d_out, int out_size, void* d_ws, size_t ws_size,
                              hipStream_t stream) {
    const float* ca = (const float*)d_in[0];   // (8,1024,1024)
    const float* nn = (const float*)d_in[1];   // (1,8,1024,1024)
    float* out = (float*)d_out;                // (8,1024,1024)

    // workspace: PH bf16 [72][H][W] (151 MB) | SegT f32 (19 MB)
    //            | Off f32 (19 MB) | Wgt f32 [8][H][W] (33.5 MB) => 222 MB
    u16*   PH   = (u16*)d_ws;
    float* SegT = (float*)((char*)d_ws + (size_t)NPL * HH * WW * sizeof(u16));
    float* Off  = SegT + (size_t)NPL * NSEG * WW;
    float* Wgt  = Off  + (size_t)NPL * NSEG * WW;

    hprefix4<<<dim3(4608 / 4), 256, 0, stream>>>(ca, nn, PH, SegT);
    segscan<<<dim3(NPL, 4), 256, 0, stream>>>(SegT, Off);
    wgtk<<<dim3(HH), 256, 0, stream>>>(ca, PH, Off, Wgt);
    vcombine3<<<dim3(HH * 4), 256, 0, stream>>>(Wgt, PH, Off, out);
}